// Round 4
// baseline (142.919 us; speedup 1.0000x reference)
//
#include <hip/hip_runtime.h>

// GenomeNet: B=4096, N_IN=W=N_OUT=1024, L=8 hidden, D=16 fan-in.
// R4: static LDS bank scheduling. Gather conflict cost per ds_read_b128 is
// the max lane-load over the 4 eight-bank groups (group = src%4 per ch-half).
// Since edge order within a node is free (sum reorder), a preprocessing
// kernel permutes each node's 16 (src,w) pairs so that at slot d, node n
// reads group (d+n)&3 when possible -> 32 consecutive nodes/wave cover each
// residue exactly 8x (balanced). Permuted tables live in d_ws (rebuilt every
// launch). Main kernel identical to R3 otherwise: fp16 rows (16 batch x 2B),
// 2 lanes/node, 2 x ds_read_b128 per edge, fp32 accumulate, fast tanh.

#define TB       16
#define W_NODES  1024
#define LAYERS   8
#define ROW_H    16                    // halfs per node row
#define BUF_H    (W_NODES * ROW_H)     // 16384 halfs = 32 KB

typedef _Float16 h8 __attribute__((ext_vector_type(8)));

__device__ __forceinline__ float fast_tanh(float x) {
    float a = __builtin_amdgcn_exp2f(x * 2.8853900817779268f);
    return 1.0f - 2.0f * __builtin_amdgcn_rcpf(a + 1.0f);
}

// ---- Preprocessing: per-row greedy slot schedule targeting group (slot+n)&3.
__global__ __launch_bounds__(256) void permute_rows(
    const int* __restrict__ src, const float* __restrict__ w,
    int* __restrict__ ps, float* __restrict__ pw, int nrows)
{
    const int rid = blockIdx.x * blockDim.x + threadIdx.x;
    if (rid >= nrows) return;
    const int n    = rid & 1023;       // node index within its layer
    const int base = rid << 4;

    int   s[16]; float wt[16];
    #pragma unroll
    for (int d = 0; d < 16; ++d) { s[d] = src[base + d]; wt[d] = w[base + d]; }

    int cnt[4] = {0, 0, 0, 0};
    int lst[4][16];
    for (int d = 0; d < 16; ++d) { const int g = s[d] & 3; lst[g][cnt[g]++] = d; }

    for (int slot = 0; slot < 16; ++slot) {
        int g = (slot + n) & 3;
        if (cnt[g] == 0) {             // desired bucket empty: steal from fullest
            g = 0;
            if (cnt[1] > cnt[g]) g = 1;
            if (cnt[2] > cnt[g]) g = 2;
            if (cnt[3] > cnt[g]) g = 3;
        }
        const int e = lst[g][--cnt[g]];
        ps[base + slot] = s[e];
        pw[base + slot] = wt[e];
    }
}

__global__ __launch_bounds__(1024) void genome_net(
    const float* __restrict__ x,
    const int*   __restrict__ src_hidden,
    const float* __restrict__ w_hidden,
    const int*   __restrict__ src_out,
    const float* __restrict__ w_out,
    float*       __restrict__ out)
{
    extern __shared__ _Float16 lds[];
    _Float16* bufA = lds;              // [1024 nodes][16 batch] fp16
    _Float16* bufB = lds + BUF_H;

    const int tid  = threadIdx.x;
    const int wave = tid >> 6;         // 0..15
    const int lane = tid & 63;
    const int nsub = lane & 31;        // node within wave-group
    const int ch   = lane >> 5;        // batch half: 0 -> b0..7, 1 -> b8..15
    const int b0   = blockIdx.x * TB;

    // ---- Stage x: fp32 -> fp16 rows.
    #pragma unroll
    for (int r = 0; r < 2; ++r) {
        const int n = (r << 9) + (wave << 5) + nsub;
        h8 hv;
        #pragma unroll
        for (int j = 0; j < 8; ++j)
            hv[j] = (_Float16)x[(size_t)(b0 + (ch << 3) + j) * W_NODES + n];
        *(h8*)(bufA + n * ROW_H + (ch << 3)) = hv;
    }
    __syncthreads();

    _Float16* rd = bufA;
    _Float16* wr = bufB;

    #pragma unroll 1
    for (int l = 0; l < LAYERS; ++l) {
        #pragma unroll 1
        for (int r = 0; r < 2; ++r) {
            const int n   = (r << 9) + (wave << 5) + nsub;
            const int row = (l << 10) + n;
            const int4*   sp = (const int4*)(src_hidden) + (row << 2);
            const float4* wp = (const float4*)(w_hidden) + (row << 2);
            int4   s4[4]; float4 w4[4];
            #pragma unroll
            for (int q = 0; q < 4; ++q) { s4[q] = sp[q]; w4[q] = wp[q]; }
            int   s_arr[16]; float w_arr[16];
            #pragma unroll
            for (int q = 0; q < 4; ++q) {
                s_arr[4*q+0] = s4[q].x; s_arr[4*q+1] = s4[q].y;
                s_arr[4*q+2] = s4[q].z; s_arr[4*q+3] = s4[q].w;
                w_arr[4*q+0] = w4[q].x; w_arr[4*q+1] = w4[q].y;
                w_arr[4*q+2] = w4[q].z; w_arr[4*q+3] = w4[q].w;
            }

            float acc[8];
            #pragma unroll
            for (int j = 0; j < 8; ++j) acc[j] = 0.0f;

            #pragma unroll
            for (int d = 0; d < 16; ++d) {
                const h8 v = *(const h8*)(rd + (s_arr[d] << 4) + (ch << 3));
                const float w = w_arr[d];
                #pragma unroll
                for (int j = 0; j < 8; ++j)
                    acc[j] = fmaf((float)v[j], w, acc[j]);
            }

            h8 hv;
            #pragma unroll
            for (int j = 0; j < 8; ++j) hv[j] = (_Float16)fast_tanh(acc[j]);
            *(h8*)(wr + n * ROW_H + (ch << 3)) = hv;
        }
        __syncthreads();
        _Float16* tmp = rd; rd = wr; wr = tmp;
    }

    // ---- Output layer: identity activation, fp32 accumulate + stores.
    #pragma unroll 1
    for (int r = 0; r < 2; ++r) {
        const int n = (r << 9) + (wave << 5) + nsub;
        const int4*   sp = (const int4*)(src_out) + (n << 2);
        const float4* wp = (const float4*)(w_out) + (n << 2);
        int4   s4[4]; float4 w4[4];
        #pragma unroll
        for (int q = 0; q < 4; ++q) { s4[q] = sp[q]; w4[q] = wp[q]; }
        int   s_arr[16]; float w_arr[16];
        #pragma unroll
        for (int q = 0; q < 4; ++q) {
            s_arr[4*q+0] = s4[q].x; s_arr[4*q+1] = s4[q].y;
            s_arr[4*q+2] = s4[q].z; s_arr[4*q+3] = s4[q].w;
            w_arr[4*q+0] = w4[q].x; w_arr[4*q+1] = w4[q].y;
            w_arr[4*q+2] = w4[q].z; w_arr[4*q+3] = w4[q].w;
        }

        float acc[8];
        #pragma unroll
        for (int j = 0; j < 8; ++j) acc[j] = 0.0f;

        #pragma unroll
        for (int d = 0; d < 16; ++d) {
            const h8 v = *(const h8*)(rd + (s_arr[d] << 4) + (ch << 3));
            const float w = w_arr[d];
            #pragma unroll
            for (int j = 0; j < 8; ++j)
                acc[j] = fmaf((float)v[j], w, acc[j]);
        }

        #pragma unroll
        for (int j = 0; j < 8; ++j)
            out[(size_t)(b0 + (ch << 3) + j) * W_NODES + n] = acc[j];
    }
}

extern "C" void kernel_launch(void* const* d_in, const int* in_sizes, int n_in,
                              void* d_out, int out_size, void* d_ws, size_t ws_size,
                              hipStream_t stream) {
    const float* x  = (const float*)d_in[0];
    const int*   sh = (const int*)  d_in[1];
    const float* wh = (const float*)d_in[2];
    const int*   so = (const int*)  d_in[3];
    const float* wo = (const float*)d_in[4];
    float* out = (float*)d_out;

    // d_ws layout: ps_hidden | pw_hidden | ps_out | pw_out
    const size_t HID = (size_t)LAYERS * W_NODES * 16;   // 131072 edges
    const size_t OUT = (size_t)W_NODES * 16;            // 16384 edges
    const size_t need = (HID + OUT) * 8;                // 1.125 MB

    const int*   sh_use = sh; const float* wh_use = wh;
    const int*   so_use = so; const float* wo_use = wo;

    if (ws_size >= need) {
        int*   ps_h = (int*)d_ws;
        float* pw_h = (float*)((char*)d_ws + HID * 4);
        int*   ps_o = (int*)((char*)d_ws + HID * 8);
        float* pw_o = (float*)((char*)d_ws + HID * 8 + OUT * 4);
        permute_rows<<<dim3((LAYERS * W_NODES + 255) / 256), dim3(256), 0, stream>>>(
            sh, wh, ps_h, pw_h, LAYERS * W_NODES);
        permute_rows<<<dim3((W_NODES + 255) / 256), dim3(256), 0, stream>>>(
            so, wo, ps_o, pw_o, W_NODES);
        sh_use = ps_h; wh_use = pw_h; so_use = ps_o; wo_use = pw_o;
    }

    const int shmem = 2 * BUF_H * (int)sizeof(_Float16);   // 65536 B
    hipFuncSetAttribute(reinterpret_cast<const void*>(genome_net),
                        hipFuncAttributeMaxDynamicSharedMemorySize, shmem);

    genome_net<<<dim3(4096 / TB), dim3(1024), shmem, stream>>>(
        x, sh_use, wh_use, so_use, wo_use, out);
}

// Round 5
// 114.746 us; speedup vs baseline: 1.2455x; 1.2455x over previous
//
#include <hip/hip_runtime.h>

// GenomeNet: B=4096, N_IN=W=N_OUT=1024, L=8 hidden, D=16 fan-in.
// R5: TB=8 batch/block, fp16 rows of 16 B. Byte offset of node s = 16*s, so
// a gather's 4-bank group = s%8 — every 32-lane half-wave can reach ALL 8
// bank groups (R3/R4's 32B rows confined each half-wave to 4 groups: ~16clk
// structural floor). One thread owns one node: 16 edges = 16 ds_read_b128.
// Grid 512 -> 2 blocks/CU (2 x 16 KB LDS each): barrier drain of one block
// overlaps LDS issue of the other. fp32 accumulate, fast tanh. No permute
// pre-pass (R4's mod-4 scheduling attacked the wrong constraint).

#define TB       8
#define W_NODES  1024
#define LAYERS   8
#define ROW_H    8                     // halfs per node row (16 B)
#define BUF_H    (W_NODES * ROW_H)     // 8192 halfs = 16 KB

typedef _Float16 h8 __attribute__((ext_vector_type(8)));

__device__ __forceinline__ float fast_tanh(float x) {
    // tanh(x) = 1 - 2/(e^{2x}+1)
    float a = __builtin_amdgcn_exp2f(x * 2.8853900817779268f);
    return 1.0f - 2.0f * __builtin_amdgcn_rcpf(a + 1.0f);
}

__global__ __launch_bounds__(1024, 8) void genome_net(
    const float* __restrict__ x,
    const int*   __restrict__ src_hidden,
    const float* __restrict__ w_hidden,
    const int*   __restrict__ src_out,
    const float* __restrict__ w_out,
    float*       __restrict__ out)
{
    extern __shared__ _Float16 lds[];
    _Float16* bufA = lds;              // [1024 nodes][8 batch] fp16, 16 KB
    _Float16* bufB = lds + BUF_H;

    const int t  = threadIdx.x;        // node / output index
    const int b0 = blockIdx.x * TB;    // batch tile base

    // ---- Stage x: fp32 -> fp16 row. Coalesced 4 KB per j across the block.
    {
        h8 hv;
        #pragma unroll
        for (int j = 0; j < TB; ++j)
            hv[j] = (_Float16)x[(size_t)(b0 + j) * W_NODES + t];
        *(h8*)(bufA + t * ROW_H) = hv;
    }
    __syncthreads();

    _Float16* rd = bufA;
    _Float16* wr = bufB;

    #pragma unroll 1
    for (int l = 0; l < LAYERS; ++l) {
        const int row = (l << 10) + t;
        const int4*   sp = (const int4*)(src_hidden) + (row << 2);
        const float4* wp = (const float4*)(w_hidden) + (row << 2);
        int4   s4[4]; float4 w4[4];
        #pragma unroll
        for (int q = 0; q < 4; ++q) { s4[q] = sp[q]; w4[q] = wp[q]; }
        int   s_arr[16]; float w_arr[16];
        #pragma unroll
        for (int q = 0; q < 4; ++q) {
            s_arr[4*q+0] = s4[q].x; s_arr[4*q+1] = s4[q].y;
            s_arr[4*q+2] = s4[q].z; s_arr[4*q+3] = s4[q].w;
            w_arr[4*q+0] = w4[q].x; w_arr[4*q+1] = w4[q].y;
            w_arr[4*q+2] = w4[q].z; w_arr[4*q+3] = w4[q].w;
        }

        float acc[TB];
        #pragma unroll
        for (int j = 0; j < TB; ++j) acc[j] = 0.0f;

        #pragma unroll
        for (int d = 0; d < 16; ++d) {
            const h8 v = *(const h8*)(rd + (s_arr[d] << 3));
            const float w = w_arr[d];
            #pragma unroll
            for (int j = 0; j < TB; ++j)
                acc[j] = fmaf((float)v[j], w, acc[j]);
        }

        h8 hv;
        #pragma unroll
        for (int j = 0; j < TB; ++j) hv[j] = (_Float16)fast_tanh(acc[j]);
        *(h8*)(wr + t * ROW_H) = hv;   // group = t%8: perfectly balanced

        __syncthreads();
        _Float16* tmp = rd; rd = wr; wr = tmp;
    }

    // ---- Output layer: identity activation, fp32 accumulate + stores.
    {
        const int4*   sp = (const int4*)(src_out) + (t << 2);
        const float4* wp = (const float4*)(w_out) + (t << 2);
        int4   s4[4]; float4 w4[4];
        #pragma unroll
        for (int q = 0; q < 4; ++q) { s4[q] = sp[q]; w4[q] = wp[q]; }
        int   s_arr[16]; float w_arr[16];
        #pragma unroll
        for (int q = 0; q < 4; ++q) {
            s_arr[4*q+0] = s4[q].x; s_arr[4*q+1] = s4[q].y;
            s_arr[4*q+2] = s4[q].z; s_arr[4*q+3] = s4[q].w;
            w_arr[4*q+0] = w4[q].x; w_arr[4*q+1] = w4[q].y;
            w_arr[4*q+2] = w4[q].z; w_arr[4*q+3] = w4[q].w;
        }

        float acc[TB];
        #pragma unroll
        for (int j = 0; j < TB; ++j) acc[j] = 0.0f;

        #pragma unroll
        for (int d = 0; d < 16; ++d) {
            const h8 v = *(const h8*)(rd + (s_arr[d] << 3));
            const float w = w_arr[d];
            #pragma unroll
            for (int j = 0; j < TB; ++j)
                acc[j] = fmaf((float)v[j], w, acc[j]);
        }

        // Coalesced 4 KB stores per j across the block.
        #pragma unroll
        for (int j = 0; j < TB; ++j)
            out[(size_t)(b0 + j) * W_NODES + t] = acc[j];
    }
}

extern "C" void kernel_launch(void* const* d_in, const int* in_sizes, int n_in,
                              void* d_out, int out_size, void* d_ws, size_t ws_size,
                              hipStream_t stream) {
    const float* x  = (const float*)d_in[0];
    const int*   sh = (const int*)  d_in[1];
    const float* wh = (const float*)d_in[2];
    const int*   so = (const int*)  d_in[3];
    const float* wo = (const float*)d_in[4];
    float* out = (float*)d_out;

    const int shmem = 2 * BUF_H * (int)sizeof(_Float16);   // 32768 B
    hipFuncSetAttribute(reinterpret_cast<const void*>(genome_net),
                        hipFuncAttributeMaxDynamicSharedMemorySize, shmem);

    genome_net<<<dim3(4096 / TB), dim3(1024), shmem, stream>>>(
        x, sh, wh, so, wo, out);
}

// Round 6
// 111.143 us; speedup vs baseline: 1.2859x; 1.0324x over previous
//
#include <hip/hip_runtime.h>

// GenomeNet: B=4096, N_IN=W=N_OUT=1024, L=8 hidden, D=16 fan-in.
// R6: R5 layout (TB=8, fp16 16B rows, group=s%8, 2 blocks/CU) + explicit
// software pipelining of the 16 edge-gathers: 8 ds_read_b128 issued up
// front, then rolling 2-ahead issue while FMAing the oldest results. Goal:
// raise per-wave outstanding LDS reads from ~2 (VGPR=32 compile) toward 8
// so the LDS pipe stays fed across waitcnt gaps. VGPR must stay <=64
// (launch_bounds 1024,8) to keep 2 blocks/CU resident.

#define TB       8
#define W_NODES  1024
#define LAYERS   8
#define ROW_H    8                     // halfs per node row (16 B)
#define BUF_H    (W_NODES * ROW_H)     // 8192 halfs = 16 KB

typedef _Float16 h8 __attribute__((ext_vector_type(8)));

__device__ __forceinline__ float fast_tanh(float x) {
    // tanh(x) = 1 - 2/(e^{2x}+1)
    float a = __builtin_amdgcn_exp2f(x * 2.8853900817779268f);
    return 1.0f - 2.0f * __builtin_amdgcn_rcpf(a + 1.0f);
}

// Gather 16 edges for one node with a software pipeline; accumulates into acc.
__device__ __forceinline__ void gather16(const _Float16* __restrict__ rd,
                                         const int* __restrict__ si,
                                         const float* __restrict__ wi,
                                         float* __restrict__ acc)
{
#define LDV(i) (*(const h8*)(rd + (si[i] << 3)))
#define FMA8(g, w)                                        \
    do {                                                  \
        const float _w = (w);                             \
        _Pragma("unroll")                                 \
        for (int j = 0; j < TB; ++j)                      \
            acc[j] = fmaf((float)(g)[j], _w, acc[j]);     \
    } while (0)

    h8 g0 = LDV(0);  h8 g1 = LDV(1);  h8 g2 = LDV(2);  h8 g3 = LDV(3);
    h8 g4 = LDV(4);  h8 g5 = LDV(5);  h8 g6 = LDV(6);  h8 g7 = LDV(7);

    FMA8(g0, wi[0]);  FMA8(g1, wi[1]);
    g0 = LDV(8);      g1 = LDV(9);
    FMA8(g2, wi[2]);  FMA8(g3, wi[3]);
    g2 = LDV(10);     g3 = LDV(11);
    FMA8(g4, wi[4]);  FMA8(g5, wi[5]);
    g4 = LDV(12);     g5 = LDV(13);
    FMA8(g6, wi[6]);  FMA8(g7, wi[7]);
    g6 = LDV(14);     g7 = LDV(15);

    FMA8(g0, wi[8]);  FMA8(g1, wi[9]);
    FMA8(g2, wi[10]); FMA8(g3, wi[11]);
    FMA8(g4, wi[12]); FMA8(g5, wi[13]);
    FMA8(g6, wi[14]); FMA8(g7, wi[15]);
#undef LDV
#undef FMA8
}

__global__ __launch_bounds__(1024, 8) void genome_net(
    const float* __restrict__ x,
    const int*   __restrict__ src_hidden,
    const float* __restrict__ w_hidden,
    const int*   __restrict__ src_out,
    const float* __restrict__ w_out,
    float*       __restrict__ out)
{
    extern __shared__ _Float16 lds[];
    _Float16* bufA = lds;              // [1024 nodes][8 batch] fp16, 16 KB
    _Float16* bufB = lds + BUF_H;

    const int t  = threadIdx.x;        // node / output index
    const int b0 = blockIdx.x * TB;    // batch tile base

    // ---- Stage x: fp32 -> fp16 row. Coalesced 4 KB per j across the block.
    {
        h8 hv;
        #pragma unroll
        for (int j = 0; j < TB; ++j)
            hv[j] = (_Float16)x[(size_t)(b0 + j) * W_NODES + t];
        *(h8*)(bufA + t * ROW_H) = hv;
    }
    __syncthreads();

    _Float16* rd = bufA;
    _Float16* wr = bufB;

    #pragma unroll 1
    for (int l = 0; l < LAYERS; ++l) {
        const int row = (l << 10) + t;
        const int4*   sp = (const int4*)(src_hidden) + (row << 2);
        const float4* wp = (const float4*)(w_hidden) + (row << 2);
        int4   s4[4]; float4 w4[4];
        #pragma unroll
        for (int q = 0; q < 4; ++q) { s4[q] = sp[q]; w4[q] = wp[q]; }
        int   si[16]; float wi[16];
        #pragma unroll
        for (int q = 0; q < 4; ++q) {
            si[4*q+0] = s4[q].x; si[4*q+1] = s4[q].y;
            si[4*q+2] = s4[q].z; si[4*q+3] = s4[q].w;
            wi[4*q+0] = w4[q].x; wi[4*q+1] = w4[q].y;
            wi[4*q+2] = w4[q].z; wi[4*q+3] = w4[q].w;
        }

        float acc[TB];
        #pragma unroll
        for (int j = 0; j < TB; ++j) acc[j] = 0.0f;

        gather16(rd, si, wi, acc);

        h8 hv;
        #pragma unroll
        for (int j = 0; j < TB; ++j) hv[j] = (_Float16)fast_tanh(acc[j]);
        *(h8*)(wr + t * ROW_H) = hv;   // group = t%8: perfectly balanced

        __syncthreads();
        _Float16* tmp = rd; rd = wr; wr = tmp;
    }

    // ---- Output layer: identity activation, fp32 accumulate + stores.
    {
        const int4*   sp = (const int4*)(src_out) + (t << 2);
        const float4* wp = (const float4*)(w_out) + (t << 2);
        int4   s4[4]; float4 w4[4];
        #pragma unroll
        for (int q = 0; q < 4; ++q) { s4[q] = sp[q]; w4[q] = wp[q]; }
        int   si[16]; float wi[16];
        #pragma unroll
        for (int q = 0; q < 4; ++q) {
            si[4*q+0] = s4[q].x; si[4*q+1] = s4[q].y;
            si[4*q+2] = s4[q].z; si[4*q+3] = s4[q].w;
            wi[4*q+0] = w4[q].x; wi[4*q+1] = w4[q].y;
            wi[4*q+2] = w4[q].z; wi[4*q+3] = w4[q].w;
        }

        float acc[TB];
        #pragma unroll
        for (int j = 0; j < TB; ++j) acc[j] = 0.0f;

        gather16(rd, si, wi, acc);

        // Coalesced 4 KB stores per j across the block.
        #pragma unroll
        for (int j = 0; j < TB; ++j)
            out[(size_t)(b0 + j) * W_NODES + t] = acc[j];
    }
}

extern "C" void kernel_launch(void* const* d_in, const int* in_sizes, int n_in,
                              void* d_out, int out_size, void* d_ws, size_t ws_size,
                              hipStream_t stream) {
    const float* x  = (const float*)d_in[0];
    const int*   sh = (const int*)  d_in[1];
    const float* wh = (const float*)d_in[2];
    const int*   so = (const int*)  d_in[3];
    const float* wo = (const float*)d_in[4];
    float* out = (float*)d_out;

    const int shmem = 2 * BUF_H * (int)sizeof(_Float16);   // 32768 B
    hipFuncSetAttribute(reinterpret_cast<const void*>(genome_net),
                        hipFuncAttributeMaxDynamicSharedMemorySize, shmem);

    genome_net<<<dim3(4096 / TB), dim3(1024), shmem, stream>>>(
        x, sh, wh, so, wo, out);
}